// Round 11
// baseline (427.141 us; speedup 1.0000x reference)
//
#include <hip/hip_runtime.h>

// Problem constants
#define B_ 8
#define C_ 128
#define HW_ 512
#define PS 16
#define E_ 16
#define NP 1024   // patches per batch (32x32)
#define FD 512
#define CH_STRIDE (HW_ * HW_)   // x channel stride in floats
#define WROW 260  // padded w LDS row (floats); GLOAD writes first 256

// d_out layout (flat f32):
// [0, 131072)        gates   [B, NP, E]
// [131072, 163840)   top_k_indices as float [B, NP, 4]
// [163840, 196608)   top_k_values [B, NP, 4]
// [196608]           aux_loss (0.0f)

__global__ void freq_kernel(const float* __restrict__ femb,
                            const float* __restrict__ fw,
                            float* __restrict__ freqf,
                            float* __restrict__ out) {
    int t = threadIdx.x;
    if (t == 0) out[196608] = 0.0f;  // aux_loss, rewritten every launch
    if (t < 128) {
        int b = t >> 4, e = t & 15;
        const float* fe = femb + b * FD;
        const float* w  = fw + e * FD;
        double s = 0.0;
        for (int i = 0; i < FD; ++i)
            s = fma((double)fe[i], (double)w[i], s);
        freqf[t] = (float)s;
    }
}

#define MAC4(ACC, XF, WF)                                       \
    ACC = __fadd_rn(ACC, __fmul_rn((XF).x, (WF).x));            \
    ACC = __fadd_rn(ACC, __fmul_rn((XF).y, (WF).y));            \
    ACC = __fadd_rn(ACC, __fmul_rn((XF).z, (WF).z));            \
    ACC = __fadd_rn(ACC, __fmul_rn((XF).w, (WF).w));

// direct global -> LDS, 16B per lane; LDS dest = uniform base + lane*16
#define GLOAD_LDS(GSRC, LDST)                                                  \
  __builtin_amdgcn_global_load_lds(                                            \
      (const __attribute__((address_space(1))) void*)(GSRC),                   \
      (__attribute__((address_space(3))) void*)(LDST), 16, 0, 0)

// Strict sequential f32 mul-then-add per (patch, expert) logit in np order
// (c outer, p, q innermost) -- per-logit rounding identical to the passing
// R3/R5 kernels. NEW: 2 patches per thread (patch lp and lp+16 of the row),
// halving per-CU w-LDS-reads and barrier events; 256 blocks = 1 per CU.
// Staging skeleton = R5 verbatim (GLOAD dbuf, issue-before-wait, counted
// vmcnt, raw double s_barrier).
__global__ __launch_bounds__(256, 1) void patch_route_kernel(
    const float* __restrict__ x,
    const float* __restrict__ noise,
    const float* __restrict__ conv_w,
    const float* __restrict__ conv_b,
    const float* __restrict__ freqf,
    float* __restrict__ out) {

  __shared__ float xs[2][16][512];    // [buf][pixel row p][512 cols] = 64 KB
  __shared__ float ws[2][16][WROW];   // [buf][expert e][256 + pad] ~33 KB
  __shared__ float slg[32][16];       // 2 KB

  const int blk  = blockIdx.x;    // 0..255
  const int b    = blk >> 5;      // batch
  const int prow = blk & 31;      // patch row 0..31 (32 patches, all 512 cols)
  const int t    = threadIdx.x;
  const int lp   = t >> 4;        // 0..15 -> patches prow*32+lp, prow*32+lp+16
  const int e    = t & 15;        // expert
  const int lp16 = lp * 16;
  const int wv   = t >> 6;        // wave 0..3
  const int lane = t & 63;

  // x base: batch b, channel 0, pixel rows prow*16.., all cols
  const float* xblk = x + (size_t)b * (C_ * CH_STRIDE)
                        + (size_t)(prow * PS) * HW_;

  // ---- stage channel 0: 8 x-GLOADs + 4 w-GLOADs per wave ----
  #pragma unroll
  for (int r = 0; r < 4; ++r) {
    const int p = wv * 4 + r;
    GLOAD_LDS(xblk + p * HW_ +       lane * 4, &xs[0][p][0]);
    GLOAD_LDS(xblk + p * HW_ + 256 + lane * 4, &xs[0][p][256]);
  }
  #pragma unroll
  for (int r = 0; r < 4; ++r) {
    const int ee = wv * 4 + r;
    GLOAD_LDS(conv_w + (size_t)ee * 32768 + lane * 4, &ws[0][ee][0]);
  }

  float acca = 0.0f, accb = 0.0f;
  for (int c = 0; c < C_; ++c) {
    const int cur = c & 1;
    if (c + 1 < C_) {
      // issue next channel's 12 loads/wave, then wait only for current's
      const int nb = cur ^ 1;
      const float* xc = xblk + (size_t)(c + 1) * CH_STRIDE;
      const float* wc = conv_w + (c + 1) * 256;
      #pragma unroll
      for (int r = 0; r < 4; ++r) {
        const int p = wv * 4 + r;
        GLOAD_LDS(xc + p * HW_ +       lane * 4, &xs[nb][p][0]);
        GLOAD_LDS(xc + p * HW_ + 256 + lane * 4, &xs[nb][p][256]);
      }
      #pragma unroll
      for (int r = 0; r < 4; ++r) {
        const int ee = wv * 4 + r;
        GLOAD_LDS(wc + (size_t)ee * 32768 + lane * 4, &ws[nb][ee][0]);
      }
      asm volatile("s_waitcnt vmcnt(12)" ::: "memory");
    } else {
      asm volatile("s_waitcnt vmcnt(0)" ::: "memory");
    }
    __builtin_amdgcn_s_barrier();          // raw: no vmcnt(0) auto-drain
    __builtin_amdgcn_sched_barrier(0);

    // consume buffer `cur`: two independent strict np-order chains
    #pragma unroll
    for (int p = 0; p < 16; ++p) {
      const float4 xa0 = *reinterpret_cast<const float4*>(&xs[cur][p][lp16 +  0]);
      const float4 xa1 = *reinterpret_cast<const float4*>(&xs[cur][p][lp16 +  4]);
      const float4 xa2 = *reinterpret_cast<const float4*>(&xs[cur][p][lp16 +  8]);
      const float4 xa3 = *reinterpret_cast<const float4*>(&xs[cur][p][lp16 + 12]);
      const float4 xb0 = *reinterpret_cast<const float4*>(&xs[cur][p][lp16 + 256]);
      const float4 xb1 = *reinterpret_cast<const float4*>(&xs[cur][p][lp16 + 260]);
      const float4 xb2 = *reinterpret_cast<const float4*>(&xs[cur][p][lp16 + 264]);
      const float4 xb3 = *reinterpret_cast<const float4*>(&xs[cur][p][lp16 + 268]);
      const float4 w0  = *reinterpret_cast<const float4*>(&ws[cur][e][p * 16 +  0]);
      const float4 w1  = *reinterpret_cast<const float4*>(&ws[cur][e][p * 16 +  4]);
      const float4 w2  = *reinterpret_cast<const float4*>(&ws[cur][e][p * 16 +  8]);
      const float4 w3  = *reinterpret_cast<const float4*>(&ws[cur][e][p * 16 + 12]);
      MAC4(acca, xa0, w0); MAC4(accb, xb0, w0);
      MAC4(acca, xa1, w1); MAC4(accb, xb1, w1);
      MAC4(acca, xa2, w2); MAC4(accb, xb2, w2);
      MAC4(acca, xa3, w3); MAC4(accb, xb3, w3);
    }

    __builtin_amdgcn_sched_barrier(0);
    __builtin_amdgcn_s_barrier();          // all waves done with `cur`
  }

  // logits, f32 adds in reference order: (+conv_b) -> (+freq) -> (+noise)
  const int patch_a = prow * 32 + lp;
  const int patch_b = patch_a + 16;
  const float cb = conv_b[e];
  const float fq = freqf[b * 16 + e];
  float lga = __fadd_rn(acca, cb);
  lga = __fadd_rn(lga, fq);
  lga = __fadd_rn(lga, noise[((size_t)b * NP + patch_a) * 16 + e]);
  float lgb = __fadd_rn(accb, cb);
  lgb = __fadd_rn(lgb, fq);
  lgb = __fadd_rn(lgb, noise[((size_t)b * NP + patch_b) * 16 + e]);

  slg[lp][e] = lga;
  slg[lp + 16][e] = lgb;
  __syncthreads();

  // ---- f32 softmax + top-4, one thread per patch (identical to round 3) ----
  if (t < 32) {
    const int pp = t;                  // local patch 0..31
    const int pat = prow * 32 + pp;    // global patch in batch
    float v[16];
    #pragma unroll
    for (int i = 0; i < 16; ++i) v[i] = slg[pp][i];

    float m = v[0];
    #pragma unroll
    for (int i = 1; i < 16; ++i) m = fmaxf(m, v[i]);

    float ex[16];
    #pragma unroll
    for (int i = 0; i < 16; ++i) ex[i] = expf(v[i] - m);

    // numpy pairwise-16 sum for the denominator
    float r[8];
    #pragma unroll
    for (int j = 0; j < 8; ++j) r[j] = __fadd_rn(ex[j], ex[j + 8]);
    float d0 = __fadd_rn(__fadd_rn(r[0], r[1]), __fadd_rn(r[2], r[3]));
    float d1 = __fadd_rn(__fadd_rn(r[4], r[5]), __fadd_rn(r[6], r[7]));
    float den = __fadd_rn(d0, d1);

    float s[16];
    #pragma unroll
    for (int i = 0; i < 16; ++i) s[i] = ex[i] / den;

    unsigned mask = 0;
    int bidx[4]; float bval[4];
    #pragma unroll
    for (int j = 0; j < 4; ++j) {
      int bi = 0; float bv = -1.0f;
      #pragma unroll
      for (int i = 0; i < 16; ++i) {
        if (!((mask >> i) & 1u) && s[i] > bv) { bv = s[i]; bi = i; }
      }
      mask |= 1u << bi;
      bidx[j] = bi; bval[j] = bv;
    }

    const size_t po = (size_t)b * NP + pat;
    float* gout = out + po * 16;
    float* iout = out + 131072 + po * 4;
    float* vout = out + 163840 + po * 4;
    #pragma unroll
    for (int j = 0; j < 4; ++j) {
      iout[j] = (float)bidx[j];
      vout[j] = bval[j];
    }
    #pragma unroll
    for (int i = 0; i < 16; ++i)
      gout[i] = ((mask >> i) & 1u) ? s[i] : 0.0f;
  }
}

extern "C" void kernel_launch(void* const* d_in, const int* in_sizes, int n_in,
                              void* d_out, int out_size, void* d_ws, size_t ws_size,
                              hipStream_t stream) {
  const float* x     = (const float*)d_in[0];
  const float* femb  = (const float*)d_in[1];
  const float* noise = (const float*)d_in[2];
  const float* cw    = (const float*)d_in[3];
  const float* cb    = (const float*)d_in[4];
  const float* fw    = (const float*)d_in[5];
  float* out = (float*)d_out;
  float* freqf = (float*)d_ws;   // 128 floats

  hipLaunchKernelGGL(freq_kernel, dim3(1), dim3(128), 0, stream,
                     femb, fw, freqf, out);
  hipLaunchKernelGGL(patch_route_kernel, dim3(256), dim3(256), 0, stream,
                     x, noise, cw, cb, freqf, out);
}

// Round 12
// 420.515 us; speedup vs baseline: 1.0158x; 1.0158x over previous
//
#include <hip/hip_runtime.h>

// Problem constants
#define B_ 8
#define C_ 128
#define HW_ 512
#define PS 16
#define E_ 16
#define NP 1024   // patches per batch (32x32)
#define FD 512
#define CH_STRIDE (HW_ * HW_)   // x channel stride in floats
#define WROW 260  // padded w LDS row: e and e+8 rows collide 2-way only (free)

// d_out layout (flat f32):
// [0, 131072)        gates   [B, NP, E]
// [131072, 163840)   top_k_indices as float [B, NP, 4]
// [163840, 196608)   top_k_values [B, NP, 4]
// [196608]           aux_loss (0.0f)

__global__ void freq_kernel(const float* __restrict__ femb,
                            const float* __restrict__ fw,
                            float* __restrict__ freqf,
                            float* __restrict__ out) {
    int t = threadIdx.x;
    if (t == 0) out[196608] = 0.0f;  // aux_loss, rewritten every launch
    if (t < 128) {
        int b = t >> 4, e = t & 15;
        const float* fe = femb + b * FD;
        const float* w  = fw + e * FD;
        double s = 0.0;
        for (int i = 0; i < FD; ++i)
            s = fma((double)fe[i], (double)w[i], s);
        freqf[t] = (float)s;
    }
}

#define MAC4(XF, WF)                                        \
    acc = __fadd_rn(acc, __fmul_rn((XF).x, (WF).x));        \
    acc = __fadd_rn(acc, __fmul_rn((XF).y, (WF).y));        \
    acc = __fadd_rn(acc, __fmul_rn((XF).z, (WF).z));        \
    acc = __fadd_rn(acc, __fmul_rn((XF).w, (WF).w));

// direct global -> LDS, 16B per lane; LDS dest = uniform base + lane*16
#define GLOAD_LDS(GSRC, LDST)                                                  \
  __builtin_amdgcn_global_load_lds(                                            \
      (const __attribute__((address_space(1))) void*)(GSRC),                   \
      (__attribute__((address_space(3))) void*)(LDST), 16, 0, 0)

// Strict sequential f32 mul-then-add per (patch, expert) logit in np order
// (c outer, p, q innermost) -- rounding identical to the passing R3/R5 runs.
// vs R5 (360us): full-row 512-thread block (1/CU, 8 waves -- same occupancy),
// TRIPLE-buffered staging with prefetch depth 2 channels and a SINGLE barrier
// per channel (the top barrier proves all waves finished MAC(c-1), making the
// stage into that buffer race-free), w staged once per CU instead of twice.
// Per-wave stage = 6 GLOADs/channel; counted s_waitcnt vmcnt(6) -> each stage
// has two full MAC phases to land.
__global__ __launch_bounds__(512, 1) void patch_route_kernel(
    const float* __restrict__ x,
    const float* __restrict__ noise,
    const float* __restrict__ conv_w,
    const float* __restrict__ conv_b,
    const float* __restrict__ freqf,
    float* __restrict__ out) {

  __shared__ float xs[3][16][512];    // [buf][pixel row p][512 cols] = 96 KB
  __shared__ float ws[3][16][WROW];   // [buf][expert e][256+pad] ~48.8 KB
  __shared__ float slg[32][16];       // 2 KB

  const int blk  = blockIdx.x;    // 0..255
  const int b    = blk >> 5;      // batch
  const int prow = blk & 31;      // patch row (32 patches, all 512 cols)
  const int t    = threadIdx.x;   // 0..511
  const int lp   = t >> 4;        // local patch 0..31
  const int e    = t & 15;        // expert
  const int lp16 = lp * 16;
  const int wv   = t >> 6;        // wave 0..7
  const int lane = t & 63;

  // x base: batch b, channel 0, pixel rows prow*16.., all 512 cols
  const float* xblk = x + (size_t)b * (C_ * CH_STRIDE)
                        + (size_t)(prow * PS) * HW_;

  // ---- stage one channel into buffer `buf`: 4 x-GLOADs + 2 w-GLOADs/wave ----
#define STAGE(CH, BUF)                                                         \
  {                                                                            \
    const float* xc = xblk + (size_t)(CH) * CH_STRIDE;                         \
    const float* wc = conv_w + (CH) * 256;                                     \
    _Pragma("unroll")                                                          \
    for (int r = 0; r < 4; ++r) {                                              \
      const int g = wv * 4 + r;          /* 0..31 */                           \
      const int p = g >> 1, half = g & 1;                                      \
      GLOAD_LDS(xc + p * HW_ + half * 256 + lane * 4,                          \
                &xs[BUF][p][half * 256]);                                      \
    }                                                                          \
    _Pragma("unroll")                                                          \
    for (int r = 0; r < 2; ++r) {                                              \
      const int ee = wv * 2 + r;         /* 0..15 */                           \
      GLOAD_LDS(wc + (size_t)ee * 32768 + lane * 4, &ws[BUF][ee][0]);          \
    }                                                                          \
  }

  // prologue: channels 0 and 1 in flight (12 GLOADs/wave outstanding)
  STAGE(0, 0)
  STAGE(1, 1)

  float acc = 0.0f;
  for (int c = 0; c < C_; ++c) {
    const int cur = c % 3;
    // entry outstanding/wave: stage(c)=6 + stage(c+1)=6 (for c<127).
    // vmcnt(6) -> channel c fully in LDS (in-order retirement).
    if (c < C_ - 1) {
      asm volatile("s_waitcnt vmcnt(6)" ::: "memory");
    } else {
      asm volatile("s_waitcnt vmcnt(0)" ::: "memory");
    }
    __builtin_amdgcn_s_barrier();       // all waves finished MAC(c-1)
    __builtin_amdgcn_sched_barrier(0);

    if (c + 2 < C_) STAGE(c + 2, (c + 2) % 3)   // into buffer freed by barrier

    // consume buffer `cur`: strict np-order chain (p outer, q inner)
    #pragma unroll
    for (int p = 0; p < 16; ++p) {
      const float4 x0 = *reinterpret_cast<const float4*>(&xs[cur][p][lp16 +  0]);
      const float4 x1 = *reinterpret_cast<const float4*>(&xs[cur][p][lp16 +  4]);
      const float4 x2 = *reinterpret_cast<const float4*>(&xs[cur][p][lp16 +  8]);
      const float4 x3 = *reinterpret_cast<const float4*>(&xs[cur][p][lp16 + 12]);
      const float4 w0 = *reinterpret_cast<const float4*>(&ws[cur][e][p * 16 +  0]);
      const float4 w1 = *reinterpret_cast<const float4*>(&ws[cur][e][p * 16 +  4]);
      const float4 w2 = *reinterpret_cast<const float4*>(&ws[cur][e][p * 16 +  8]);
      const float4 w3 = *reinterpret_cast<const float4*>(&ws[cur][e][p * 16 + 12]);
      MAC4(x0, w0);
      MAC4(x1, w1);
      MAC4(x2, w2);
      MAC4(x3, w3);
    }
    __builtin_amdgcn_sched_barrier(0);
    // single barrier per channel: next iteration's top barrier guards reuse
  }

  // logits, f32 adds in reference order: (+conv_b) -> (+freq) -> (+noise)
  const int patch = prow * 32 + lp;
  float lg = __fadd_rn(acc, conv_b[e]);
  lg = __fadd_rn(lg, freqf[b * 16 + e]);
  lg = __fadd_rn(lg, noise[((size_t)b * NP + patch) * 16 + e]);

  slg[lp][e] = lg;
  __syncthreads();

  // ---- f32 softmax + top-4, one thread per patch (identical to round 3) ----
  if (t < 32) {
    const int pp = t;
    const int pat = prow * 32 + pp;
    float v[16];
    #pragma unroll
    for (int i = 0; i < 16; ++i) v[i] = slg[pp][i];

    float m = v[0];
    #pragma unroll
    for (int i = 1; i < 16; ++i) m = fmaxf(m, v[i]);

    float ex[16];
    #pragma unroll
    for (int i = 0; i < 16; ++i) ex[i] = expf(v[i] - m);

    // numpy pairwise-16 sum for the denominator
    float r[8];
    #pragma unroll
    for (int j = 0; j < 8; ++j) r[j] = __fadd_rn(ex[j], ex[j + 8]);
    float d0 = __fadd_rn(__fadd_rn(r[0], r[1]), __fadd_rn(r[2], r[3]));
    float d1 = __fadd_rn(__fadd_rn(r[4], r[5]), __fadd_rn(r[6], r[7]));
    float den = __fadd_rn(d0, d1);

    float s[16];
    #pragma unroll
    for (int i = 0; i < 16; ++i) s[i] = ex[i] / den;

    unsigned mask = 0;
    int bidx[4]; float bval[4];
    #pragma unroll
    for (int j = 0; j < 4; ++j) {
      int bi = 0; float bv = -1.0f;
      #pragma unroll
      for (int i = 0; i < 16; ++i) {
        if (!((mask >> i) & 1u) && s[i] > bv) { bv = s[i]; bi = i; }
      }
      mask |= 1u << bi;
      bidx[j] = bi; bval[j] = bv;
    }

    const size_t po = (size_t)b * NP + pat;
    float* gout = out + po * 16;
    float* iout = out + 131072 + po * 4;
    float* vout = out + 163840 + po * 4;
    #pragma unroll
    for (int j = 0; j < 4; ++j) {
      iout[j] = (float)bidx[j];
      vout[j] = bval[j];
    }
    #pragma unroll
    for (int i = 0; i < 16; ++i)
      gout[i] = ((mask >> i) & 1u) ? s[i] : 0.0f;
  }
}

extern "C" void kernel_launch(void* const* d_in, const int* in_sizes, int n_in,
                              void* d_out, int out_size, void* d_ws, size_t ws_size,
                              hipStream_t stream) {
  const float* x     = (const float*)d_in[0];
  const float* femb  = (const float*)d_in[1];
  const float* noise = (const float*)d_in[2];
  const float* cw    = (const float*)d_in[3];
  const float* cb    = (const float*)d_in[4];
  const float* fw    = (const float*)d_in[5];
  float* out = (float*)d_out;
  float* freqf = (float*)d_ws;   // 128 floats

  hipLaunchKernelGGL(freq_kernel, dim3(1), dim3(128), 0, stream,
                     femb, fw, freqf, out);
  hipLaunchKernelGGL(patch_route_kernel, dim3(256), dim3(512), 0, stream,
                     x, noise, cw, cb, freqf, out);
}

// Round 13
// 366.586 us; speedup vs baseline: 1.1652x; 1.1471x over previous
//
#include <hip/hip_runtime.h>

// Problem constants
#define B_ 8
#define C_ 128
#define HW_ 512
#define PS 16
#define E_ 16
#define NP 1024   // patches per batch (32x32)
#define FD 512
#define CH_STRIDE (HW_ * HW_)   // x channel stride in floats
#define WROW 260  // w LDS row stride: (e,e+8) 2-way only = optimal for 16x16B

// d_out layout (flat f32):
// [0, 131072)        gates   [B, NP, E]
// [131072, 163840)   top_k_indices as float [B, NP, 4]
// [163840, 196608)   top_k_values [B, NP, 4]
// [196608]           aux_loss (0.0f)

__global__ void freq_kernel(const float* __restrict__ femb,
                            const float* __restrict__ fw,
                            float* __restrict__ freqf,
                            float* __restrict__ out) {
    int t = threadIdx.x;
    if (t == 0) out[196608] = 0.0f;  // aux_loss, rewritten every launch
    if (t < 128) {
        int b = t >> 4, e = t & 15;
        const float* fe = femb + b * FD;
        const float* w  = fw + e * FD;
        double s = 0.0;
        for (int i = 0; i < FD; ++i)
            s = fma((double)fe[i], (double)w[i], s);
        freqf[t] = (float)s;
    }
}

#define MAC4(XF, WF)                                        \
    acc = __fadd_rn(acc, __fmul_rn((XF).x, (WF).x));        \
    acc = __fadd_rn(acc, __fmul_rn((XF).y, (WF).y));        \
    acc = __fadd_rn(acc, __fmul_rn((XF).z, (WF).z));        \
    acc = __fadd_rn(acc, __fmul_rn((XF).w, (WF).w));

// direct global -> LDS, 16B per lane; LDS dest = uniform base + lane*16
#define GLOAD_LDS(GSRC, LDST)                                                  \
  __builtin_amdgcn_global_load_lds(                                            \
      (const __attribute__((address_space(1))) void*)(GSRC),                   \
      (__attribute__((address_space(3))) void*)(LDST), 16, 0, 0)

// Strict sequential f32 mul-then-add per (patch, expert) logit in np order
// (c outer, p, q innermost) -- rounding identical to the passing R3/R5 runs.
// Structure = R5 verbatim (the measured best: GLOAD dbuf, issue-before-wait,
// counted vmcnt(8), raw double s_barrier, 2 blocks/CU). ONE change: x is
// staged into LDS in [p][k(q-chunk)][lp] interleaved order via per-lane
// SOURCE swizzle (gload_lds writes linearly; swizzle the global address).
// Old layout: 4 lp-groups read addrs 64 floats apart -> all bank 0 = 4-way
// conflict on EVERY x-read. New layout: thread reads at lp*4 + k*64 ->
// bank-start 4*lp, all 16 banks distinct across the wave = conflict-free.
__global__ __launch_bounds__(256, 2) void patch_route_kernel(
    const float* __restrict__ x,
    const float* __restrict__ noise,
    const float* __restrict__ conv_w,
    const float* __restrict__ conv_b,
    const float* __restrict__ freqf,
    float* __restrict__ out) {

  __shared__ float xs[2][16][256];    // [buf][p][k*16+lp interleaved] 32 KB
  __shared__ float ws[2][16][WROW];   // [buf][expert e][256 + pad] ~33 KB
  __shared__ float slg[16][16];

  const int blk = blockIdx.x;     // 0..511
  const int b   = blk >> 6;
  const int pg  = blk & 63;       // patch group of 16
  const int t   = threadIdx.x;
  const int lp  = t >> 4;         // local patch 0..15
  const int e   = t & 15;         // expert
  const int lp4 = lp * 4;
  const int patch = pg * 16 + lp;        // 0..1023
  const int pi = pg >> 1;                // patch row
  const int wv   = t >> 6;               // wave 0..3
  const int lane = t & 63;

  // source swizzle for x staging: LDS slot l (16B) <- global float4 chunk
  // g = (l&15)*4 + (l>>4)  i.e. float offset (l&15)*16 + (l>>4)*4
  const int xsw = (lane & 15) * 16 + (lane >> 4) * 4;

  // block x base: batch b, channel 0, pixel row pi*16, col (pg&1)*256
  const float* xblk = x + (size_t)b * (C_ * CH_STRIDE)
                        + (size_t)(pi * PS) * HW_ + (pg & 1) * 256;

  // ---- stage channel 0 (8 GLOADs per wave) ----
  {
    #pragma unroll
    for (int r = 0; r < 4; ++r) {
      const int p = wv * 4 + r;
      GLOAD_LDS(xblk + p * HW_ + xsw, &xs[0][p][0]);
    }
    #pragma unroll
    for (int r = 0; r < 4; ++r) {
      const int ee = wv * 4 + r;
      GLOAD_LDS(conv_w + (size_t)ee * 32768 + lane * 4, &ws[0][ee][0]);
    }
  }

  float acc = 0.0f;
  for (int c = 0; c < C_; ++c) {
    const int cur = c & 1;
    if (c + 1 < C_) {
      // issue next channel's 8 loads/wave, then wait only for current's
      const int nb = cur ^ 1;
      const float* xc = xblk + (size_t)(c + 1) * CH_STRIDE;
      const float* wc = conv_w + (c + 1) * 256;
      #pragma unroll
      for (int r = 0; r < 4; ++r) {
        const int p = wv * 4 + r;
        GLOAD_LDS(xc + p * HW_ + xsw, &xs[nb][p][0]);
      }
      #pragma unroll
      for (int r = 0; r < 4; ++r) {
        const int ee = wv * 4 + r;
        GLOAD_LDS(wc + (size_t)ee * 32768 + lane * 4, &ws[nb][ee][0]);
      }
      asm volatile("s_waitcnt vmcnt(8)" ::: "memory");
    } else {
      asm volatile("s_waitcnt vmcnt(0)" ::: "memory");
    }
    __builtin_amdgcn_s_barrier();          // raw: no vmcnt(0) auto-drain
    __builtin_amdgcn_sched_barrier(0);

    // consume buffer `cur`: strict np-order chain (p outer, q=k inner)
    #pragma unroll
    for (int p = 0; p < 16; ++p) {
      const float4 x0 = *reinterpret_cast<const float4*>(&xs[cur][p][lp4 +   0]);
      const float4 x1 = *reinterpret_cast<const float4*>(&xs[cur][p][lp4 +  64]);
      const float4 x2 = *reinterpret_cast<const float4*>(&xs[cur][p][lp4 + 128]);
      const float4 x3 = *reinterpret_cast<const float4*>(&xs[cur][p][lp4 + 192]);
      const float4 w0 = *reinterpret_cast<const float4*>(&ws[cur][e][p * 16 +  0]);
      const float4 w1 = *reinterpret_cast<const float4*>(&ws[cur][e][p * 16 +  4]);
      const float4 w2 = *reinterpret_cast<const float4*>(&ws[cur][e][p * 16 +  8]);
      const float4 w3 = *reinterpret_cast<const float4*>(&ws[cur][e][p * 16 + 12]);
      MAC4(x0, w0);
      MAC4(x1, w1);
      MAC4(x2, w2);
      MAC4(x3, w3);
    }

    __builtin_amdgcn_sched_barrier(0);
    __builtin_amdgcn_s_barrier();          // all waves done with `cur`
  }

  // logits, f32 adds in reference order: (+conv_b) -> (+freq) -> (+noise)
  float lg = __fadd_rn(acc, conv_b[e]);
  lg = __fadd_rn(lg, freqf[b * 16 + e]);
  lg = __fadd_rn(lg, noise[((size_t)b * NP + patch) * 16 + e]);

  slg[lp][e] = lg;
  __syncthreads();

  // ---- f32 softmax + top-4, one thread per patch (identical to round 3) ----
  if (t < 16) {
    const int pp = t;
    const int pat = pg * 16 + pp;
    float v[16];
    #pragma unroll
    for (int i = 0; i < 16; ++i) v[i] = slg[pp][i];

    float m = v[0];
    #pragma unroll
    for (int i = 1; i < 16; ++i) m = fmaxf(m, v[i]);

    float ex[16];
    #pragma unroll
    for (int i = 0; i < 16; ++i) ex[i] = expf(v[i] - m);

    // numpy pairwise-16 sum for the denominator
    float r[8];
    #pragma unroll
    for (int j = 0; j < 8; ++j) r[j] = __fadd_rn(ex[j], ex[j + 8]);
    float d0 = __fadd_rn(__fadd_rn(r[0], r[1]), __fadd_rn(r[2], r[3]));
    float d1 = __fadd_rn(__fadd_rn(r[4], r[5]), __fadd_rn(r[6], r[7]));
    float den = __fadd_rn(d0, d1);

    float s[16];
    #pragma unroll
    for (int i = 0; i < 16; ++i) s[i] = ex[i] / den;

    unsigned mask = 0;
    int bidx[4]; float bval[4];
    #pragma unroll
    for (int j = 0; j < 4; ++j) {
      int bi = 0; float bv = -1.0f;
      #pragma unroll
      for (int i = 0; i < 16; ++i) {
        if (!((mask >> i) & 1u) && s[i] > bv) { bv = s[i]; bi = i; }
      }
      mask |= 1u << bi;
      bidx[j] = bi; bval[j] = bv;
    }

    const size_t po = (size_t)b * NP + pat;
    float* gout = out + po * 16;
    float* iout = out + 131072 + po * 4;
    float* vout = out + 163840 + po * 4;
    #pragma unroll
    for (int j = 0; j < 4; ++j) {
      iout[j] = (float)bidx[j];
      vout[j] = bval[j];
    }
    #pragma unroll
    for (int i = 0; i < 16; ++i)
      gout[i] = ((mask >> i) & 1u) ? s[i] : 0.0f;
  }
}

extern "C" void kernel_launch(void* const* d_in, const int* in_sizes, int n_in,
                              void* d_out, int out_size, void* d_ws, size_t ws_size,
                              hipStream_t stream) {
  const float* x     = (const float*)d_in[0];
  const float* femb  = (const float*)d_in[1];
  const float* noise = (const float*)d_in[2];
  const float* cw    = (const float*)d_in[3];
  const float* cb    = (const float*)d_in[4];
  const float* fw    = (const float*)d_in[5];
  float* out = (float*)d_out;
  float* freqf = (float*)d_ws;   // 128 floats

  hipLaunchKernelGGL(freq_kernel, dim3(1), dim3(128), 0, stream,
                     femb, fw, freqf, out);
  hipLaunchKernelGGL(patch_route_kernel, dim3(512), dim3(256), 0, stream,
                     x, noise, cw, cb, freqf, out);
}